// Round 1
// baseline (16.635 us; speedup 1.0000x reference)
//
#include <hip/hip_runtime.h>

// geo landmark loss:
//   diff[b,row] = id_base[row]·(alpha[b]-ref_alpha[b]) + exp_base[row]·(delta[b]-delta_pred[b])
//   loss = sum_{b,l,c} w[l] * diff[b, 3*lm[l]+c]^2 / 68
// Only 204 rows of each base are touched -> latency-bound tiny kernel.

#define NUM_LM 68
#define BATCH 64
#define K_ID 80
#define K_EXP 64

__device__ __constant__ int LM_IDX[NUM_LM] = {
    27440, 27208, 27608, 27816, 35472, 34766, 34312, 34022, 33838, 33654,
    33375, 32939, 32244, 16264, 16467, 16888, 16644, 31716, 31056, 30662,
    30454, 30288, 29549, 29382, 29177, 28787, 28111,  8161,  8177,  8187,
     8192,  9883,  9163,  8204,  7243,  6515, 14066, 12383, 11353, 10455,
    11492, 12653,  5828,  4920,  3886,  2215,  3640,  4801, 10795, 10395,
     8935,  8215,  7495,  6025,  5522,  6915,  7636,  8236,  8836,  9555,
    10537,  9064,  8223,  7384,  5909,  7629,  8229,  8829
};

__global__ void geo_loss_kernel(const float* __restrict__ alpha,
                                const float* __restrict__ delta,
                                const float* __restrict__ ref_alpha,
                                const float* __restrict__ delta_pred,
                                const float* __restrict__ id_base,
                                const float* __restrict__ exp_base,
                                float* __restrict__ out) {
    const int bid = blockIdx.x;          // 0..203 : (landmark, coord)
    const int l   = bid / 3;
    const int c   = bid - 3 * l;
    const long long row = 3LL * LM_IDX[l] + c;
    const int b   = threadIdx.x;         // batch = lane (wave64)

    const float* __restrict__ idr = id_base  + row * K_ID;
    const float* __restrict__ exr = exp_base + row * K_EXP;
    const float* __restrict__ a   = alpha      + b * K_ID;
    const float* __restrict__ ra  = ref_alpha  + b * K_ID;
    const float* __restrict__ d   = delta      + b * K_EXP;
    const float* __restrict__ dp  = delta_pred + b * K_EXP;

    float diff = 0.0f;
    #pragma unroll 8
    for (int k = 0; k < K_ID; ++k)
        diff = fmaf(idr[k], a[k] - ra[k], diff);
    #pragma unroll 8
    for (int k = 0; k < K_EXP; ++k)
        diff = fmaf(exr[k], d[k] - dp[k], diff);

    const float w = ((l >= 17 && l < 27) || l >= 36) ? 50.0f : 1.0f;
    float v = w * diff * diff;

    // wave64 butterfly reduction across batches
    #pragma unroll
    for (int off = 32; off > 0; off >>= 1)
        v += __shfl_down(v, off, 64);

    if (b == 0)
        atomicAdd(out, v * (1.0f / 68.0f));
}

extern "C" void kernel_launch(void* const* d_in, const int* in_sizes, int n_in,
                              void* d_out, int out_size, void* d_ws, size_t ws_size,
                              hipStream_t stream) {
    const float* alpha      = (const float*)d_in[0];
    const float* delta      = (const float*)d_in[1];
    const float* ref_alpha  = (const float*)d_in[2];
    const float* delta_pred = (const float*)d_in[3];
    const float* id_base    = (const float*)d_in[4];
    const float* exp_base   = (const float*)d_in[5];
    float* out = (float*)d_out;

    // harness poisons d_out to 0xAA and never re-zeros between replays
    hipMemsetAsync(out, 0, sizeof(float), stream);

    geo_loss_kernel<<<dim3(NUM_LM * 3), dim3(BATCH), 0, stream>>>(
        alpha, delta, ref_alpha, delta_pred, id_base, exp_base, out);
}

// Round 2
// 14.217 us; speedup vs baseline: 1.1700x; 1.1700x over previous
//
#include <hip/hip_runtime.h>

// geo landmark loss, 2-dispatch:
//   prep:   zero out, coeff diffs transposed -> ws[k][b]   (coalesced writes)
//   loss:   204 blocks (one per landmark-row), 64 lanes = 64 batches,
//           coalesced coeff reads, wave-uniform base reads, 4-way ILP chain,
//           butterfly reduce, one atomicAdd per block.

#define NUM_LM 68
#define K_ID 80
#define K_EXP 64

__device__ __constant__ int LM_IDX[NUM_LM] = {
    27440, 27208, 27608, 27816, 35472, 34766, 34312, 34022, 33838, 33654,
    33375, 32939, 32244, 16264, 16467, 16888, 16644, 31716, 31056, 30662,
    30454, 30288, 29549, 29382, 29177, 28787, 28111,  8161,  8177,  8187,
     8192,  9883,  9163,  8204,  7243,  6515, 14066, 12383, 11353, 10455,
    11492, 12653,  5828,  4920,  3886,  2215,  3640,  4801, 10795, 10395,
     8935,  8215,  7495,  6025,  5522,  6915,  7636,  8236,  8836,  9555,
    10537,  9064,  8223,  7384,  5909,  7629,  8229,  8829
};

// 5120 id-coeff elements + 4096 exp-coeff elements = 9216 total
__global__ __launch_bounds__(256) void prep_kernel(
        const float* __restrict__ alpha,
        const float* __restrict__ delta,
        const float* __restrict__ ref_alpha,
        const float* __restrict__ delta_pred,
        float* __restrict__ ws,
        float* __restrict__ out) {
    const int idx = blockIdx.x * 256 + threadIdx.x;
    if (idx == 0) out[0] = 0.0f;
    if (idx < 64 * K_ID) {
        const int b = idx / K_ID;
        const int k = idx - b * K_ID;
        ws[k * 64 + b] = alpha[idx] - ref_alpha[idx];     // daT[k][b]
    } else {
        const int j = idx - 64 * K_ID;                     // < 4096
        const int b = j >> 6;
        const int k = j & 63;
        ws[(K_ID + k) * 64 + b] = delta[j] - delta_pred[j]; // ddT[k][b]
    }
}

__global__ __launch_bounds__(64) void loss_kernel(
        const float* __restrict__ id_base,
        const float* __restrict__ exp_base,
        const float* __restrict__ ws,
        float* __restrict__ out) {
    const int bid = blockIdx.x;          // 0..203 : (landmark, coord)
    const int l   = bid / 3;
    const int c   = bid - 3 * l;
    const long long row = 3LL * LM_IDX[l] + c;
    const int t   = threadIdx.x;         // batch = lane

    const float* __restrict__ idr = id_base  + row * K_ID;   // wave-uniform
    const float* __restrict__ exr = exp_base + row * K_EXP;  // wave-uniform
    const float* __restrict__ cid = ws + t;                  // daT[k][b=t]
    const float* __restrict__ cex = ws + K_ID * 64 + t;      // ddT[k][b=t]

    float d0 = 0.f, d1 = 0.f, d2 = 0.f, d3 = 0.f;
    #pragma unroll
    for (int k = 0; k < K_ID; k += 4) {
        d0 = fmaf(idr[k + 0], cid[(k + 0) * 64], d0);
        d1 = fmaf(idr[k + 1], cid[(k + 1) * 64], d1);
        d2 = fmaf(idr[k + 2], cid[(k + 2) * 64], d2);
        d3 = fmaf(idr[k + 3], cid[(k + 3) * 64], d3);
    }
    #pragma unroll
    for (int k = 0; k < K_EXP; k += 4) {
        d0 = fmaf(exr[k + 0], cex[(k + 0) * 64], d0);
        d1 = fmaf(exr[k + 1], cex[(k + 1) * 64], d1);
        d2 = fmaf(exr[k + 2], cex[(k + 2) * 64], d2);
        d3 = fmaf(exr[k + 3], cex[(k + 3) * 64], d3);
    }
    const float diff = (d0 + d1) + (d2 + d3);

    const float w = ((l >= 17 && l < 27) || l >= 36) ? 50.0f : 1.0f;
    float v = w * diff * diff;

    #pragma unroll
    for (int off = 32; off > 0; off >>= 1)
        v += __shfl_down(v, off, 64);

    if (t == 0)
        atomicAdd(out, v * (1.0f / 68.0f));
}

extern "C" void kernel_launch(void* const* d_in, const int* in_sizes, int n_in,
                              void* d_out, int out_size, void* d_ws, size_t ws_size,
                              hipStream_t stream) {
    const float* alpha      = (const float*)d_in[0];
    const float* delta      = (const float*)d_in[1];
    const float* ref_alpha  = (const float*)d_in[2];
    const float* delta_pred = (const float*)d_in[3];
    const float* id_base    = (const float*)d_in[4];
    const float* exp_base   = (const float*)d_in[5];
    float* out = (float*)d_out;
    float* ws  = (float*)d_ws;   // needs 9216 floats = 36,864 B

    prep_kernel<<<dim3((64 * (K_ID + K_EXP)) / 256), dim3(256), 0, stream>>>(
        alpha, delta, ref_alpha, delta_pred, ws, out);

    loss_kernel<<<dim3(NUM_LM * 3), dim3(64), 0, stream>>>(
        id_base, exp_base, ws, out);
}